// Round 12
// baseline (240.038 us; speedup 1.0000x reference)
//
#include <hip/hip_runtime.h>
#include <math.h>

#define EPSD 1e-5

// ---------------- reduction helpers ----------------

__device__ __forceinline__ double waveReduceSumD(double v) {   // result in lane 0
#pragma unroll
    for (int off = 32; off > 0; off >>= 1)
        v += __shfl_down(v, off, 64);
    return v;
}

template <int NW>
__device__ __forceinline__ double blockReduceSumD(double v, double* buf) {
    int lane = threadIdx.x & 63;
    int w = threadIdx.x >> 6;
    v = waveReduceSumD(v);
    __syncthreads();
    if (lane == 0) buf[w] = v;
    __syncthreads();
    double tot = 0.0;
#pragma unroll
    for (int i = 0; i < NW; i++) tot += buf[i];
    return tot;
}

// Build 26-entry entropy table: tab[cnt] = -(cnt/25)*log(clip(cnt/25,1e-5,1-1e-5))
__device__ __forceinline__ void build_ent_tab(float* tab) {
    int t = threadIdx.x;
    if (t < 26) {
        if (t == 0) tab[0] = 0.f;
        else {
            double pk = (double)t / 25.0;
            double cl = fmin(fmax(pk, 1e-5), 1.0 - 1e-5);
            tab[t] = (float)(-pk * log(cl));
        }
    }
}

// entropy of one 5x5 patch at (py,px) of an 18x18 channel slab in LDS
__device__ __forceinline__ float patch_ent(const float* ch, int py, int px, const float* tab) {
    float pv[25];
#pragma unroll
    for (int i = 0; i < 5; i++)
#pragma unroll
        for (int j = 0; j < 5; j++)
            pv[i * 5 + j] = ch[(py + i) * 18 + px + j];
    float mn = pv[0], mx = pv[0];
#pragma unroll
    for (int k = 1; k < 25; k++) { mn = fminf(mn, pv[k]); mx = fmaxf(mx, pv[k]); }
    float rng = (mx > mn) ? (mx - mn) : 1.0f;
    unsigned long long a0 = 0ull, a1 = 0ull;
    int a2 = 0;
#pragma unroll
    for (int k = 0; k < 25; k++) {
        float tt = (pv[k] - mn) / rng * 25.0f;   // keep reference op order
        int bi = (int)floorf(tt);
        bi = bi < 0 ? 0 : (bi > 24 ? 24 : bi);
        unsigned sh0 = ((unsigned)(5 * bi)) & 63u;
        unsigned sh1 = ((unsigned)(5 * bi - 60)) & 63u;
        a0 += (bi < 12) ? (1ull << sh0) : 0ull;
        a1 += (bi >= 12 && bi < 24) ? (1ull << sh1) : 0ull;
        a2 += (bi == 24) ? 1 : 0;
    }
    float ent = 0.f;
#pragma unroll
    for (int k = 0; k < 12; k++) ent += tab[(a0 >> (5 * k)) & 31ull];
#pragma unroll
    for (int k = 0; k < 12; k++) ent += tab[(a1 >> (5 * k)) & 31ull];
    ent += tab[a2];
    return ent;
}

// ---------------- kA: conv0 (all 8 ch) — 2-out-row tiles, 10 KB LDS ----------------
// grid (28, 64): block = (2-out-row tile, image), 128 threads (112 conv-active).
// ky loop NOT unrolled: per-iteration weight set = 56 floats -> fits SGPRs, so the
// scalar loads pipeline instead of serializing in giant batches.
__global__ __launch_bounds__(128, 4) void k_conv0(const float* __restrict__ x,
                                                  const float* __restrict__ w,
                                                  const float* __restrict__ bias,
                                                  float* __restrict__ h0raw,
                                                  double* __restrict__ part0) {
    __shared__ __align__(16) float tile[2508];   // 11 rows * 228 slots (one ci)
    __shared__ double redbuf[2][16];
    int tl = blockIdx.x;
    int b = blockIdx.y;
    int t = threadIdx.x;
    for (int i = t; i < 2508; i += 128) tile[i] = 0.f;
    int y_base = tl * 8 - 2;
    const float* xb = x + (size_t)b * 150528;
    float acc[8];
#pragma unroll
    for (int c = 0; c < 8; c++) acc[c] = bias[c];
    int ry = t / 56, ox = t % 56;   // used when t<112
    for (int ci = 0; ci < 3; ci++) {
        __syncthreads();   // protect tile from previous round's readers
        for (int i = t; i < 616; i += 128) {      // 11 rows * 56 float4
            int r = i / 56, f4 = i % 56;
            int yIn = y_base + r;
            if (yIn >= 0 && yIn < 224) {
                float4 v = *(const float4*)&xb[ci * 50176 + yIn * 224 + f4 * 4];
                float* tp = tile + r * 228;
                tp[114 + f4] = v.x;   // pc=4f4+2 -> slot 2*57+f4
                tp[171 + f4] = v.y;   // pc=4f4+3 -> slot 3*57+f4
                tp[f4 + 1]   = v.z;   // pc=4f4+4 -> slot 0*57+f4+1
                tp[58 + f4]  = v.w;   // pc=4f4+5 -> slot 1*57+f4+1
            }
        }
        __syncthreads();
        if (t < 112) {
            const float* wci = w + ci * 49;       // uniform -> s_load
#pragma unroll 1
            for (int ky = 0; ky < 7; ky++) {      // NOT unrolled: 56-weight batches
                const float* rp = tile + (4 * ry + ky) * 228;
#pragma unroll
                for (int kx = 0; kx < 7; kx++) {
                    float v = rp[(kx & 3) * 57 + ox + (kx >> 2)];
#pragma unroll
                    for (int c = 0; c < 8; c++)
                        acc[c] += v * wci[c * 147 + ky * 7 + kx];
                }
            }
        }
    }
    if (t < 112) {
        int oy = tl * 2 + ry;
        int opix = oy * 56 + ox;
#pragma unroll
        for (int c = 0; c < 8; c++)
            h0raw[((size_t)b * 8 + c) * 3136 + opix] = acc[c];
    } else {
#pragma unroll
        for (int c = 0; c < 8; c++) acc[c] = 0.f;   // inactive: contribute 0 to stats
    }
    int wv = t >> 6, lane = t & 63;
#pragma unroll
    for (int c = 0; c < 8; c++) {
        double rs = waveReduceSumD((double)acc[c]);
        double rq = waveReduceSumD((double)acc[c] * (double)acc[c]);
        if (lane == 0) { redbuf[wv][c * 2] = rs; redbuf[wv][c * 2 + 1] = rq; }
    }
    __syncthreads();
    if (t < 16) {
        double tot = redbuf[0][t] + redbuf[1][t];
        part0[(((size_t)b * 28 + tl) << 4) + t] = tot;   // [b][tile(28)][c*2+k]
    }
}

// ---------------- kB: conv1 (8->16, 5x5, s3, p1) + entropy-IN + ReLU ----------------
// Block = (b, group of 4 out-channels): 256 blocks, 1024 threads (16 waves).
__global__ __launch_bounds__(1024) void k_conv1_ent(const float* __restrict__ h0raw,
                                                    const double* __restrict__ part0,
                                                    const float* __restrict__ gw,
                                                    const float* __restrict__ gb,
                                                    const float* __restrict__ w,
                                                    const float* __restrict__ bias,
                                                    const float* __restrict__ nw,
                                                    const float* __restrict__ nb,
                                                    float* __restrict__ h1) {
    __shared__ __align__(16) float xin2[25088];   // [4 ci-pair][3136 px][2]
    __shared__ float vals[1296];    // 4 * 324
    __shared__ float tab[26];
    __shared__ float gnp[16];       // gnsc[0..7], gnsh[8..15]
    __shared__ double redbuf[16][2];
    __shared__ double entbuf[16];
    __shared__ float prm[4][3];     // mu, sc, beta per local channel
    int b = blockIdx.x >> 2;
    int grp = blockIdx.x & 3;
    int t = threadIdx.x;
    if (t < 8) {   // GN fold for input channel t of image b
        double s = 0.0, s2 = 0.0;
        const double* p = part0 + ((size_t)b * 28) * 16;
        for (int tile = 0; tile < 28; tile++) {
            s += p[tile * 16 + t * 2];
            s2 += p[tile * 16 + t * 2 + 1];
        }
        double mean = s / 3136.0;
        double var = s2 / 3136.0 - mean * mean;   // biased (GN)
        double rstd = 1.0 / sqrt(var + EPSD);
        double sc = (double)gw[t] * rstd;
        gnp[t] = (float)sc;
        gnp[8 + t] = (float)((double)gb[t] - mean * sc);
    }
    build_ent_tab(tab);
    __syncthreads();
    for (int i = t; i < 25088; i += 1024) {
        int ci = i / 3136, px = i - ci * 3136;
        float v = fmaxf(h0raw[(size_t)b * 25088 + i] * gnp[ci] + gnp[8 + ci], 0.f);
        xin2[(ci >> 1) * 6272 + px * 2 + (ci & 1)] = v;
    }
    __syncthreads();

    int wv = t >> 6, lane = t & 63;
    int c = wv >> 2;          // local out-channel 0..3
    int q = wv & 3;           // quarter of the 324 px
    int j_u = __builtin_amdgcn_readfirstlane(grp * 4 + c);   // SGPR channel id
    const float* wg = w + (size_t)j_u * 200;                 // uniform -> s_load
    float* vch = vals + c * 324;
    float bv = bias[j_u];
    double s = 0.0, s2 = 0.0;
    for (int p = q * 81 + lane; p < q * 81 + 81; p += 64) {
        int oy = p / 18, ox = p - oy * 18;
        int y0 = oy * 3 - 1, x0 = ox * 3 - 1;
        float acc = bv;
        if (oy >= 1 && ox >= 1) {
#pragma unroll
            for (int c2 = 0; c2 < 4; c2++) {
                const float* xp = xin2 + c2 * 6272 + (y0 * 56 + x0) * 2;
                const float* wp0 = wg + (2 * c2) * 25;
#pragma unroll
                for (int ky = 0; ky < 5; ky++)
#pragma unroll
                    for (int kx = 0; kx < 5; kx++) {
                        float2 v = *(const float2*)&xp[(ky * 56 + kx) * 2];
                        acc += v.x * wp0[ky * 5 + kx];
                        acc += v.y * wp0[25 + ky * 5 + kx];
                    }
            }
        } else {
            int ky0 = y0 < 0 ? 1 : 0;
            int kx0 = x0 < 0 ? 1 : 0;
            for (int c2 = 0; c2 < 4; c2++) {
                const float* xp = xin2 + c2 * 6272;
                const float* wp0 = wg + (2 * c2) * 25;
                for (int ky = ky0; ky < 5; ky++) {
                    for (int kx = kx0; kx < 5; kx++) {
                        float2 v = *(const float2*)&xp[((y0 + ky) * 56 + x0 + kx) * 2];
                        acc += v.x * wp0[ky * 5 + kx];
                        acc += v.y * wp0[25 + ky * 5 + kx];
                    }
                }
            }
        }
        vch[p] = acc;
        s += (double)acc; s2 += (double)acc * (double)acc;
    }
    s = waveReduceSumD(s);
    s2 = waveReduceSumD(s2);
    if (lane == 0) { redbuf[wv][0] = s; redbuf[wv][1] = s2; }
    __syncthreads();   // vals complete + stats partials visible
    double ent = 0.0;
    if (lane < 49) {
        int pi = q * 49 + lane;
        ent = (double)patch_ent(vch, pi / 14, pi % 14, tab);
    }
    ent = waveReduceSumD(ent);
    if (lane == 0) entbuf[wv] = ent;
    __syncthreads();
    if (t < 4) {
        double ss = 0.0, qq = 0.0, ee = 0.0;
        for (int k = 0; k < 4; k++) {
            ss += redbuf[t * 4 + k][0];
            qq += redbuf[t * 4 + k][1];
            ee += entbuf[t * 4 + k];
        }
        double entmean = ee / 196.0;
        double mean = ss / 324.0;
        double varb = qq / 324.0 - mean * mean;
        double varu = varb * (324.0 / 323.0);   // unbiased (torch default)
        double rstd = 1.0 / sqrt(varu + EPSD);
        prm[t][0] = (float)mean;
        prm[t][1] = (float)((double)nw[grp * 4 + t] * entmean * rstd);
        prm[t][2] = nb[grp * 4 + t];
    }
    __syncthreads();
    float* outp = h1 + ((size_t)b * 16 + grp * 4) * 324;
    for (int i = t; i < 1296; i += 1024) {
        int cc = i / 324;
        outp[i] = fmaxf((vals[i] - prm[cc][0]) * prm[cc][1] + prm[cc][2], 0.f);
    }
}

// ---------------- kC: conv2 (16->32, 3x3, s1, p1) + entropy-IN + ReLU ----------------
// One block per (b, c): 2048 blocks, 256 threads. xin channel-pair interleaved.
__global__ __launch_bounds__(256) void k_conv2_ent(const float* __restrict__ in,
                                                   const float* __restrict__ w,
                                                   const float* __restrict__ bias,
                                                   const float* __restrict__ nw,
                                                   const float* __restrict__ nb,
                                                   float* __restrict__ out) {
    __shared__ __align__(16) float xin2[5184];   // [8 pair][324 px][2]
    __shared__ float vals[324];
    __shared__ float tab[26];
    __shared__ double rbuf[4];
    int b = blockIdx.x >> 5;
    int c = blockIdx.x & 31;      // uniform
    int t = threadIdx.x;
    const float* xb = in + (size_t)b * 5184;
    for (int i = t; i < 5184; i += 256) {
        int ci = i / 324, px = i - ci * 324;
        xin2[(ci >> 1) * 648 + px * 2 + (ci & 1)] = xb[i];
    }
    build_ent_tab(tab);
    __syncthreads();
    const float* wc = w + c * 144;    // uniform base -> s_load on unrolled indices
    float bv = bias[c];
    double s = 0.0, s2 = 0.0;
    {   // interior: 256 px, one per thread
        int oy = 1 + (t >> 4), ox = 1 + (t & 15);
        int base = ((oy - 1) * 18 + (ox - 1)) * 2;
        float acc = bv;
#pragma unroll
        for (int c2 = 0; c2 < 8; c2++) {
            const float* xp = xin2 + c2 * 648 + base;
            const float* wp = wc + c2 * 18;
#pragma unroll
            for (int ky = 0; ky < 3; ky++)
#pragma unroll
                for (int kx = 0; kx < 3; kx++) {
                    float2 v = *(const float2*)&xp[(ky * 18 + kx) * 2];
                    acc += v.x * wp[ky * 3 + kx];
                    acc += v.y * wp[9 + ky * 3 + kx];
                }
        }
        vals[oy * 18 + ox] = acc;
        s += (double)acc; s2 += (double)acc * (double)acc;
    }
    if (t < 68) {   // boundary px
        int oy, ox;
        if (t < 18)      { oy = 0;      ox = t; }
        else if (t < 36) { oy = 17;     ox = t - 18; }
        else if (t < 52) { oy = t - 35; ox = 0; }
        else             { oy = t - 51; ox = 17; }
        int y0 = oy - 1, x0 = ox - 1;
        int ky0 = y0 < 0 ? 1 : 0;
        int ky1 = (18 - y0) < 3 ? 2 : 3;
        int kx0 = x0 < 0 ? 1 : 0;
        int kx1 = (18 - x0) < 3 ? 2 : 3;
        float acc = bv;
        for (int c2 = 0; c2 < 8; c2++) {
            const float* xp = xin2 + c2 * 648;
            const float* wp = wc + c2 * 18;
            for (int ky = ky0; ky < ky1; ky++) {
                for (int kx = kx0; kx < kx1; kx++) {
                    float2 v = *(const float2*)&xp[((y0 + ky) * 18 + x0 + kx) * 2];
                    acc += v.x * wp[ky * 3 + kx];
                    acc += v.y * wp[9 + ky * 3 + kx];
                }
            }
        }
        vals[oy * 18 + ox] = acc;
        s += (double)acc; s2 += (double)acc * (double)acc;
    }
    __syncthreads();
    double ent = 0.0;
    if (t < 196) ent = (double)patch_ent(vals, t / 14, t % 14, tab);
    double entmean = blockReduceSumD<4>(ent, rbuf) / 196.0;
    double ssum  = blockReduceSumD<4>(s, rbuf);
    double s2sum = blockReduceSumD<4>(s2, rbuf);
    double mean = ssum / 324.0;
    double varb = s2sum / 324.0 - mean * mean;
    double varu = varb * (324.0 / 323.0);
    double rstd = 1.0 / sqrt(varu + EPSD);
    float sc = (float)((double)nw[c] * entmean * rstd);
    float mu = (float)mean;
    float be = nb[c];
    float* outp = out + ((size_t)b * 32 + c) * 324;
    for (int idx = t; idx < 324; idx += 256)
        outp[idx] = fmaxf((vals[idx] - mu) * sc + be, 0.f);
}

// ---------------- kD: BatchNorm1d stats -> scale/shift. 162 blocks, 4-way batch split ----
__global__ __launch_bounds__(256) void k_bnstats(const float* __restrict__ h2,
                                                 const float* __restrict__ g,
                                                 const float* __restrict__ bb,
                                                 float* __restrict__ scale,
                                                 float* __restrict__ shift) {
    __shared__ double sb[4][64], qb[4][64];
    int lane = threadIdx.x & 63;
    int q = threadIdx.x >> 6;
    int f = blockIdx.x * 64 + lane;
    double s = 0.0, s2 = 0.0;
    for (int b = q * 16; b < q * 16 + 16; b++) {
        double v = (double)h2[(size_t)b * 10368 + f];
        s += v; s2 += v * v;
    }
    sb[q][lane] = s; qb[q][lane] = s2;
    __syncthreads();
    if (threadIdx.x < 64) {
        double S = sb[0][lane] + sb[1][lane] + sb[2][lane] + sb[3][lane];
        double Q = qb[0][lane] + qb[1][lane] + qb[2][lane] + qb[3][lane];
        double mean = S / 64.0;
        double var = Q / 64.0 - mean * mean;   // biased (BN training)
        double rstd = 1.0 / sqrt(var + EPSD);
        double sc = (double)g[f] * rstd;
        scale[f] = (float)sc;
        shift[f] = (float)((double)bb[f] - mean * sc);
    }
}

// ---------------- kE: fused fc1 (BN-folded) + ReLU + heads + softmax ----------------
// One block per image: 64 blocks, 1024 threads (16 waves). hv staged once in LDS;
// wave wv computes output neurons 2wv, 2wv+1; thread 0 finishes the softmax heads.
__global__ __launch_bounds__(1024) void k_fc_heads(const float* __restrict__ h2,
                                                   const float* __restrict__ scale,
                                                   const float* __restrict__ shift,
                                                   const float* __restrict__ w1,
                                                   const float* __restrict__ b1,
                                                   const float* __restrict__ sw,
                                                   const float* __restrict__ sb,
                                                   const float* __restrict__ vw,
                                                   const float* __restrict__ vb,
                                                   float* __restrict__ out) {
    __shared__ __align__(16) float hv[10368];
    __shared__ double dbuf[32];
    int b = blockIdx.x;
    int t = threadIdx.x;
    const float* hb = h2 + (size_t)b * 10368;
    for (int i = t * 4; i < 10368; i += 4096) {
        float4 h4 = *(const float4*)&hb[i];
        float4 s4 = *(const float4*)&scale[i];
        float4 t4 = *(const float4*)&shift[i];
        float4 r;
        r.x = h4.x * s4.x + t4.x;
        r.y = h4.y * s4.y + t4.y;
        r.z = h4.z * s4.z + t4.z;
        r.w = h4.w * s4.w + t4.w;
        *(float4*)&hv[i] = r;
    }
    __syncthreads();
    int wv = t >> 6, lane = t & 63;
#pragma unroll
    for (int k = 0; k < 2; k++) {
        int j = wv * 2 + k;
        const float* wj = w1 + (size_t)j * 10368;
        double acc = 0.0;
        for (int i = lane * 4; i < 10368; i += 256) {
            float4 x4 = *(const float4*)&hv[i];
            float4 w4 = *(const float4*)&wj[i];
            acc += (double)(x4.x * w4.x);
            acc += (double)(x4.y * w4.y);
            acc += (double)(x4.z * w4.z);
            acc += (double)(x4.w * w4.w);
        }
        acc = waveReduceSumD(acc);
        if (lane == 0) dbuf[j] = acc;
    }
    __syncthreads();
    if (t == 0) {
        double h[32];
#pragma unroll
        for (int j = 0; j < 32; j++)
            h[j] = (double)(float)fmax(dbuf[j] + (double)b1[j], 0.0);   // match prior f32 fc store
        double lg[5];
        double mx = -1e300;
#pragma unroll
        for (int k = 0; k < 5; k++) {
            double a = (double)sb[k];
#pragma unroll
            for (int i = 0; i < 32; i++) a += h[i] * (double)sw[k * 32 + i];
            lg[k] = a;
            mx = fmax(mx, a);
        }
        double se = 0.0;
#pragma unroll
        for (int k = 0; k < 5; k++) { lg[k] = exp(lg[k] - mx); se += lg[k]; }
#pragma unroll
        for (int k = 0; k < 5; k++) out[b * 5 + k] = (float)(lg[k] / se);
        double l0 = (double)vb[0], l1 = (double)vb[1];
#pragma unroll
        for (int i = 0; i < 32; i++) { l0 += h[i] * (double)vw[i]; l1 += h[i] * (double)vw[32 + i]; }
        double m = fmax(l0, l1);
        double e0 = exp(l0 - m), e1 = exp(l1 - m);
        double inv = 1.0 / (e0 + e1);
        out[320 + b * 2 + 0] = (float)(e0 * inv);
        out[320 + b * 2 + 1] = (float)(e1 * inv);
    }
}

// ---------------- host launcher ----------------
extern "C" void kernel_launch(void* const* d_in, const int* in_sizes, int n_in,
                              void* d_out, int out_size, void* d_ws, size_t ws_size,
                              hipStream_t stream) {
    const float* x       = (const float*)d_in[0];
    const float* conv0_w = (const float*)d_in[1];
    const float* conv0_b = (const float*)d_in[2];
    const float* conv1_w = (const float*)d_in[3];
    const float* conv1_b = (const float*)d_in[4];
    const float* conv2_w = (const float*)d_in[5];
    const float* conv2_b = (const float*)d_in[6];
    const float* gn0_w   = (const float*)d_in[7];
    const float* gn0_b   = (const float*)d_in[8];
    const float* n1_w    = (const float*)d_in[9];
    const float* n1_b    = (const float*)d_in[10];
    const float* n2_w    = (const float*)d_in[11];
    const float* n2_b    = (const float*)d_in[12];
    const float* bn_g    = (const float*)d_in[13];
    const float* bn_b    = (const float*)d_in[14];
    const float* fc1_w   = (const float*)d_in[15];
    const float* fc1_b   = (const float*)d_in[16];
    const float* shape_w = (const float*)d_in[17];
    const float* shape_b = (const float*)d_in[18];
    const float* vern_w  = (const float*)d_in[19];
    const float* vern_b  = (const float*)d_in[20];
    float* out = (float*)d_out;

    // workspace: doubles first (alignment), then floats
    double* part0 = (double*)d_ws;               // 64*28*16 = 28672 doubles
    float* fbase   = (float*)(part0 + 28672);
    float* h0raw   = fbase;                      // 1605632
    float* h1      = h0raw + 1605632;            // 331776
    float* h2      = h1 + 331776;                // 663552
    float* bnscale = h2 + 663552;                // 10368
    float* bnshift = bnscale + 10368;            // 10368

    k_conv0<<<dim3(28, 64), dim3(128), 0, stream>>>(x, conv0_w, conv0_b, h0raw, part0);
    k_conv1_ent<<<dim3(256), dim3(1024), 0, stream>>>(h0raw, part0, gn0_w, gn0_b,
                                                      conv1_w, conv1_b, n1_w, n1_b, h1);
    k_conv2_ent<<<dim3(2048), dim3(256), 0, stream>>>(h1, conv2_w, conv2_b, n2_w, n2_b, h2);
    k_bnstats<<<dim3(162), dim3(256), 0, stream>>>(h2, bn_g, bn_b, bnscale, bnshift);
    k_fc_heads<<<dim3(64), dim3(1024), 0, stream>>>(h2, bnscale, bnshift, fc1_w, fc1_b,
                                                    shape_w, shape_b, vern_w, vern_b, out);
}

// Round 13
// 216.395 us; speedup vs baseline: 1.1093x; 1.1093x over previous
//
#include <hip/hip_runtime.h>
#include <math.h>

#define EPSD 1e-5

// ---------------- reduction helpers ----------------

__device__ __forceinline__ double waveReduceSumD(double v) {   // result in lane 0
#pragma unroll
    for (int off = 32; off > 0; off >>= 1)
        v += __shfl_down(v, off, 64);
    return v;
}

template <int NW>
__device__ __forceinline__ double blockReduceSumD(double v, double* buf) {
    int lane = threadIdx.x & 63;
    int w = threadIdx.x >> 6;
    v = waveReduceSumD(v);
    __syncthreads();
    if (lane == 0) buf[w] = v;
    __syncthreads();
    double tot = 0.0;
#pragma unroll
    for (int i = 0; i < NW; i++) tot += buf[i];
    return tot;
}

// Build 26-entry entropy table: tab[cnt] = -(cnt/25)*log(clip(cnt/25,1e-5,1-1e-5))
__device__ __forceinline__ void build_ent_tab(float* tab) {
    int t = threadIdx.x;
    if (t < 26) {
        if (t == 0) tab[0] = 0.f;
        else {
            double pk = (double)t / 25.0;
            double cl = fmin(fmax(pk, 1e-5), 1.0 - 1e-5);
            tab[t] = (float)(-pk * log(cl));
        }
    }
}

// entropy of one 5x5 patch at (py,px) of an 18x18 channel slab in LDS.
// Division hoisted: one 25/rng per patch instead of 25 divides (bin-boundary
// rounding may differ from the reference in rare ties; ~1e-3 output effect max).
__device__ __forceinline__ float patch_ent(const float* ch, int py, int px, const float* tab) {
    float pv[25];
#pragma unroll
    for (int i = 0; i < 5; i++)
#pragma unroll
        for (int j = 0; j < 5; j++)
            pv[i * 5 + j] = ch[(py + i) * 18 + px + j];
    float mn = pv[0], mx = pv[0];
#pragma unroll
    for (int k = 1; k < 25; k++) { mn = fminf(mn, pv[k]); mx = fmaxf(mx, pv[k]); }
    float rng = (mx > mn) ? (mx - mn) : 1.0f;
    float scl = 25.0f / rng;
    unsigned long long a0 = 0ull, a1 = 0ull;
    int a2 = 0;
#pragma unroll
    for (int k = 0; k < 25; k++) {
        float tt = (pv[k] - mn) * scl;
        int bi = (int)floorf(tt);
        bi = bi < 0 ? 0 : (bi > 24 ? 24 : bi);
        unsigned sh0 = ((unsigned)(5 * bi)) & 63u;
        unsigned sh1 = ((unsigned)(5 * bi - 60)) & 63u;
        a0 += (bi < 12) ? (1ull << sh0) : 0ull;
        a1 += (bi >= 12 && bi < 24) ? (1ull << sh1) : 0ull;
        a2 += (bi == 24) ? 1 : 0;
    }
    float ent = 0.f;
#pragma unroll
    for (int k = 0; k < 12; k++) ent += tab[(a0 >> (5 * k)) & 31ull];
#pragma unroll
    for (int k = 0; k < 12; k++) ent += tab[(a1 >> (5 * k)) & 31ull];
    ent += tab[a2];
    return ent;
}

// ---------------- kA: conv0 (all 8 ch) — 2-out-row tiles, 10 KB LDS ----------------
// grid (28, 64): block = (2-out-row tile, image), 128 threads (112 conv-active).
__global__ __launch_bounds__(128, 4) void k_conv0(const float* __restrict__ x,
                                                  const float* __restrict__ w,
                                                  const float* __restrict__ bias,
                                                  float* __restrict__ h0raw,
                                                  double* __restrict__ part0) {
    __shared__ __align__(16) float tile[2508];   // 11 rows * 228 slots (one ci)
    __shared__ double redbuf[2][16];
    int tl = blockIdx.x;
    int b = blockIdx.y;
    int t = threadIdx.x;
    for (int i = t; i < 2508; i += 128) tile[i] = 0.f;
    int y_base = tl * 8 - 2;
    const float* xb = x + (size_t)b * 150528;
    float acc[8];
#pragma unroll
    for (int c = 0; c < 8; c++) acc[c] = bias[c];
    int ry = t / 56, ox = t % 56;   // used when t<112
    for (int ci = 0; ci < 3; ci++) {
        __syncthreads();   // protect tile from previous round's readers
        for (int i = t; i < 616; i += 128) {      // 11 rows * 56 float4
            int r = i / 56, f4 = i % 56;
            int yIn = y_base + r;
            if (yIn >= 0 && yIn < 224) {
                float4 v = *(const float4*)&xb[ci * 50176 + yIn * 224 + f4 * 4];
                float* tp = tile + r * 228;
                tp[114 + f4] = v.x;   // pc=4f4+2 -> slot 2*57+f4
                tp[171 + f4] = v.y;   // pc=4f4+3 -> slot 3*57+f4
                tp[f4 + 1]   = v.z;   // pc=4f4+4 -> slot 0*57+f4+1
                tp[58 + f4]  = v.w;   // pc=4f4+5 -> slot 1*57+f4+1
            }
        }
        __syncthreads();
        if (t < 112) {
            const float* wci = w + ci * 49;       // uniform -> s_load
#pragma unroll 1
            for (int ky = 0; ky < 7; ky++) {      // NOT unrolled: 56-weight batches
                const float* rp = tile + (4 * ry + ky) * 228;
#pragma unroll
                for (int kx = 0; kx < 7; kx++) {
                    float v = rp[(kx & 3) * 57 + ox + (kx >> 2)];
#pragma unroll
                    for (int c = 0; c < 8; c++)
                        acc[c] += v * wci[c * 147 + ky * 7 + kx];
                }
            }
        }
    }
    if (t < 112) {
        int oy = tl * 2 + ry;
        int opix = oy * 56 + ox;
#pragma unroll
        for (int c = 0; c < 8; c++)
            h0raw[((size_t)b * 8 + c) * 3136 + opix] = acc[c];
    } else {
#pragma unroll
        for (int c = 0; c < 8; c++) acc[c] = 0.f;   // inactive: contribute 0 to stats
    }
    int wv = t >> 6, lane = t & 63;
#pragma unroll
    for (int c = 0; c < 8; c++) {
        double rs = waveReduceSumD((double)acc[c]);
        double rq = waveReduceSumD((double)acc[c] * (double)acc[c]);
        if (lane == 0) { redbuf[wv][c * 2] = rs; redbuf[wv][c * 2 + 1] = rq; }
    }
    __syncthreads();
    if (t < 16) {
        double tot = redbuf[0][t] + redbuf[1][t];
        part0[(((size_t)b * 28 + tl) << 4) + t] = tot;   // [b][tile(28)][c*2+k]
    }
}

// ---------------- kB: conv1 (8->16, 5x5, s3, p1) + entropy-IN + ReLU ----------------
// Block = (b, group of 4 out-channels): 256 blocks, 1024 threads (16 waves).
__global__ __launch_bounds__(1024) void k_conv1_ent(const float* __restrict__ h0raw,
                                                    const double* __restrict__ part0,
                                                    const float* __restrict__ gw,
                                                    const float* __restrict__ gb,
                                                    const float* __restrict__ w,
                                                    const float* __restrict__ bias,
                                                    const float* __restrict__ nw,
                                                    const float* __restrict__ nb,
                                                    float* __restrict__ h1) {
    __shared__ __align__(16) float xin2[25088];   // [4 ci-pair][3136 px][2]
    __shared__ float vals[1296];    // 4 * 324
    __shared__ float tab[26];
    __shared__ float gnp[16];       // gnsc[0..7], gnsh[8..15]
    __shared__ double redbuf[16][2];
    __shared__ double entbuf[16];
    __shared__ float prm[4][3];     // mu, sc, beta per local channel
    int b = blockIdx.x >> 2;
    int grp = blockIdx.x & 3;
    int t = threadIdx.x;
    if (t < 8) {   // GN fold for input channel t of image b
        double s = 0.0, s2 = 0.0;
        const double* p = part0 + ((size_t)b * 28) * 16;
        for (int tile = 0; tile < 28; tile++) {
            s += p[tile * 16 + t * 2];
            s2 += p[tile * 16 + t * 2 + 1];
        }
        double mean = s / 3136.0;
        double var = s2 / 3136.0 - mean * mean;   // biased (GN)
        double rstd = 1.0 / sqrt(var + EPSD);
        double sc = (double)gw[t] * rstd;
        gnp[t] = (float)sc;
        gnp[8 + t] = (float)((double)gb[t] - mean * sc);
    }
    build_ent_tab(tab);
    __syncthreads();
    for (int i = t; i < 25088; i += 1024) {
        int ci = i / 3136, px = i - ci * 3136;
        float v = fmaxf(h0raw[(size_t)b * 25088 + i] * gnp[ci] + gnp[8 + ci], 0.f);
        xin2[(ci >> 1) * 6272 + px * 2 + (ci & 1)] = v;
    }
    __syncthreads();

    int wv = t >> 6, lane = t & 63;
    int c = wv >> 2;          // local out-channel 0..3
    int q = wv & 3;           // quarter of the 324 px
    int j_u = __builtin_amdgcn_readfirstlane(grp * 4 + c);   // SGPR channel id
    const float* wg = w + (size_t)j_u * 200;                 // uniform -> s_load
    float* vch = vals + c * 324;
    float bv = bias[j_u];
    double s = 0.0, s2 = 0.0;
    for (int p = q * 81 + lane; p < q * 81 + 81; p += 64) {
        int oy = p / 18, ox = p - oy * 18;
        int y0 = oy * 3 - 1, x0 = ox * 3 - 1;
        float acc = bv;
        if (oy >= 1 && ox >= 1) {
#pragma unroll
            for (int c2 = 0; c2 < 4; c2++) {
                const float* xp = xin2 + c2 * 6272 + (y0 * 56 + x0) * 2;
                const float* wp0 = wg + (2 * c2) * 25;
#pragma unroll
                for (int ky = 0; ky < 5; ky++)
#pragma unroll
                    for (int kx = 0; kx < 5; kx++) {
                        float2 v = *(const float2*)&xp[(ky * 56 + kx) * 2];
                        acc += v.x * wp0[ky * 5 + kx];
                        acc += v.y * wp0[25 + ky * 5 + kx];
                    }
            }
        } else {
            int ky0 = y0 < 0 ? 1 : 0;
            int kx0 = x0 < 0 ? 1 : 0;
            for (int c2 = 0; c2 < 4; c2++) {
                const float* xp = xin2 + c2 * 6272;
                const float* wp0 = wg + (2 * c2) * 25;
                for (int ky = ky0; ky < 5; ky++) {
                    for (int kx = kx0; kx < 5; kx++) {
                        float2 v = *(const float2*)&xp[((y0 + ky) * 56 + x0 + kx) * 2];
                        acc += v.x * wp0[ky * 5 + kx];
                        acc += v.y * wp0[25 + ky * 5 + kx];
                    }
                }
            }
        }
        vch[p] = acc;
        s += (double)acc; s2 += (double)acc * (double)acc;
    }
    s = waveReduceSumD(s);
    s2 = waveReduceSumD(s2);
    if (lane == 0) { redbuf[wv][0] = s; redbuf[wv][1] = s2; }
    __syncthreads();   // vals complete + stats partials visible
    double ent = 0.0;
    if (lane < 49) {
        int pi = q * 49 + lane;
        ent = (double)patch_ent(vch, pi / 14, pi % 14, tab);
    }
    ent = waveReduceSumD(ent);
    if (lane == 0) entbuf[wv] = ent;
    __syncthreads();
    if (t < 4) {
        double ss = 0.0, qq = 0.0, ee = 0.0;
        for (int k = 0; k < 4; k++) {
            ss += redbuf[t * 4 + k][0];
            qq += redbuf[t * 4 + k][1];
            ee += entbuf[t * 4 + k];
        }
        double entmean = ee / 196.0;
        double mean = ss / 324.0;
        double varb = qq / 324.0 - mean * mean;
        double varu = varb * (324.0 / 323.0);   // unbiased (torch default)
        double rstd = 1.0 / sqrt(varu + EPSD);
        prm[t][0] = (float)mean;
        prm[t][1] = (float)((double)nw[grp * 4 + t] * entmean * rstd);
        prm[t][2] = nb[grp * 4 + t];
    }
    __syncthreads();
    float* outp = h1 + ((size_t)b * 16 + grp * 4) * 324;
    for (int i = t; i < 1296; i += 1024) {
        int cc = i / 324;
        outp[i] = fmaxf((vals[i] - prm[cc][0]) * prm[cc][1] + prm[cc][2], 0.f);
    }
}

// ---------------- kC: conv2 (16->32, 3x3, s1, p1) + entropy-IN + ReLU ----------------
// One block per (b, c): 2048 blocks, 256 threads. xin channel-pair interleaved.
__global__ __launch_bounds__(256) void k_conv2_ent(const float* __restrict__ in,
                                                   const float* __restrict__ w,
                                                   const float* __restrict__ bias,
                                                   const float* __restrict__ nw,
                                                   const float* __restrict__ nb,
                                                   float* __restrict__ out) {
    __shared__ __align__(16) float xin2[5184];   // [8 pair][324 px][2]
    __shared__ float vals[324];
    __shared__ float tab[26];
    __shared__ double rbuf[4];
    int b = blockIdx.x >> 5;
    int c = blockIdx.x & 31;      // uniform
    int t = threadIdx.x;
    const float* xb = in + (size_t)b * 5184;
    for (int i = t; i < 5184; i += 256) {
        int ci = i / 324, px = i - ci * 324;
        xin2[(ci >> 1) * 648 + px * 2 + (ci & 1)] = xb[i];
    }
    build_ent_tab(tab);
    __syncthreads();
    const float* wc = w + c * 144;    // uniform base -> s_load on unrolled indices
    float bv = bias[c];
    double s = 0.0, s2 = 0.0;
    {   // interior: 256 px, one per thread
        int oy = 1 + (t >> 4), ox = 1 + (t & 15);
        int base = ((oy - 1) * 18 + (ox - 1)) * 2;
        float acc = bv;
#pragma unroll
        for (int c2 = 0; c2 < 8; c2++) {
            const float* xp = xin2 + c2 * 648 + base;
            const float* wp = wc + c2 * 18;
#pragma unroll
            for (int ky = 0; ky < 3; ky++)
#pragma unroll
                for (int kx = 0; kx < 3; kx++) {
                    float2 v = *(const float2*)&xp[(ky * 18 + kx) * 2];
                    acc += v.x * wp[ky * 3 + kx];
                    acc += v.y * wp[9 + ky * 3 + kx];
                }
        }
        vals[oy * 18 + ox] = acc;
        s += (double)acc; s2 += (double)acc * (double)acc;
    }
    if (t < 68) {   // boundary px
        int oy, ox;
        if (t < 18)      { oy = 0;      ox = t; }
        else if (t < 36) { oy = 17;     ox = t - 18; }
        else if (t < 52) { oy = t - 35; ox = 0; }
        else             { oy = t - 51; ox = 17; }
        int y0 = oy - 1, x0 = ox - 1;
        int ky0 = y0 < 0 ? 1 : 0;
        int ky1 = (18 - y0) < 3 ? 2 : 3;
        int kx0 = x0 < 0 ? 1 : 0;
        int kx1 = (18 - x0) < 3 ? 2 : 3;
        float acc = bv;
        for (int c2 = 0; c2 < 8; c2++) {
            const float* xp = xin2 + c2 * 648;
            const float* wp = wc + c2 * 18;
            for (int ky = ky0; ky < ky1; ky++) {
                for (int kx = kx0; kx < kx1; kx++) {
                    float2 v = *(const float2*)&xp[((y0 + ky) * 18 + x0 + kx) * 2];
                    acc += v.x * wp[ky * 3 + kx];
                    acc += v.y * wp[9 + ky * 3 + kx];
                }
            }
        }
        vals[oy * 18 + ox] = acc;
        s += (double)acc; s2 += (double)acc * (double)acc;
    }
    __syncthreads();
    double ent = 0.0;
    if (t < 196) ent = (double)patch_ent(vals, t / 14, t % 14, tab);
    double entmean = blockReduceSumD<4>(ent, rbuf) / 196.0;
    double ssum  = blockReduceSumD<4>(s, rbuf);
    double s2sum = blockReduceSumD<4>(s2, rbuf);
    double mean = ssum / 324.0;
    double varb = s2sum / 324.0 - mean * mean;
    double varu = varb * (324.0 / 323.0);
    double rstd = 1.0 / sqrt(varu + EPSD);
    float sc = (float)((double)nw[c] * entmean * rstd);
    float mu = (float)mean;
    float be = nb[c];
    float* outp = out + ((size_t)b * 32 + c) * 324;
    for (int idx = t; idx < 324; idx += 256)
        outp[idx] = fmaxf((vals[idx] - mu) * sc + be, 0.f);
}

// ---------------- kD: BatchNorm1d stats -> scale/shift. 162 blocks, 4-way batch split ----
__global__ __launch_bounds__(256) void k_bnstats(const float* __restrict__ h2,
                                                 const float* __restrict__ g,
                                                 const float* __restrict__ bb,
                                                 float* __restrict__ scale,
                                                 float* __restrict__ shift) {
    __shared__ double sb[4][64], qb[4][64];
    int lane = threadIdx.x & 63;
    int q = threadIdx.x >> 6;
    int f = blockIdx.x * 64 + lane;
    double s = 0.0, s2 = 0.0;
    for (int b = q * 16; b < q * 16 + 16; b++) {
        double v = (double)h2[(size_t)b * 10368 + f];
        s += v; s2 += v * v;
    }
    sb[q][lane] = s; qb[q][lane] = s2;
    __syncthreads();
    if (threadIdx.x < 64) {
        double S = sb[0][lane] + sb[1][lane] + sb[2][lane] + sb[3][lane];
        double Q = qb[0][lane] + qb[1][lane] + qb[2][lane] + qb[3][lane];
        double mean = S / 64.0;
        double var = Q / 64.0 - mean * mean;   // biased (BN training)
        double rstd = 1.0 / sqrt(var + EPSD);
        double sc = (double)g[f] * rstd;
        scale[f] = (float)sc;
        shift[f] = (float)((double)bb[f] - mean * sc);
    }
}

// ---------------- kE: fc1 with folded BN, + ReLU (float4 loads) ----------------
__global__ __launch_bounds__(256) void k_fc1(const float* __restrict__ h2,
                                             const float* __restrict__ scale,
                                             const float* __restrict__ shift,
                                             const float* __restrict__ w1,
                                             const float* __restrict__ b1,
                                             float* __restrict__ fcout) {
    __shared__ double rbuf[4];
    int b = blockIdx.x >> 5;
    int j = blockIdx.x & 31;
    const float* hb = h2 + (size_t)b * 10368;
    const float* wj = w1 + (size_t)j * 10368;
    double acc = 0.0;
    for (int f = threadIdx.x * 4; f < 10368; f += 1024) {
        float4 h4 = *(const float4*)&hb[f];
        float4 s4 = *(const float4*)&scale[f];
        float4 t4 = *(const float4*)&shift[f];
        float4 w4 = *(const float4*)&wj[f];
        acc += (double)((h4.x * s4.x + t4.x) * w4.x);
        acc += (double)((h4.y * s4.y + t4.y) * w4.y);
        acc += (double)((h4.z * s4.z + t4.z) * w4.z);
        acc += (double)((h4.w * s4.w + t4.w) * w4.w);
    }
    acc = blockReduceSumD<4>(acc, rbuf);
    if (threadIdx.x == 0)
        fcout[b * 32 + j] = (float)fmax(acc + (double)b1[j], 0.0);
}

// ---------------- kF: heads + softmax ----------------
__global__ __launch_bounds__(64) void k_heads(const float* __restrict__ fc,
                                              const float* __restrict__ sw,
                                              const float* __restrict__ sb,
                                              const float* __restrict__ vw,
                                              const float* __restrict__ vb,
                                              float* __restrict__ out) {
    int b = threadIdx.x;
    double h[32];
#pragma unroll
    for (int i = 0; i < 32; i++) h[i] = (double)fc[b * 32 + i];
    double lg[5];
    double mx = -1e300;
#pragma unroll
    for (int k = 0; k < 5; k++) {
        double a = (double)sb[k];
#pragma unroll
        for (int i = 0; i < 32; i++) a += h[i] * (double)sw[k * 32 + i];
        lg[k] = a;
        mx = fmax(mx, a);
    }
    double se = 0.0;
#pragma unroll
    for (int k = 0; k < 5; k++) { lg[k] = exp(lg[k] - mx); se += lg[k]; }
#pragma unroll
    for (int k = 0; k < 5; k++) out[b * 5 + k] = (float)(lg[k] / se);
    double l0 = (double)vb[0], l1 = (double)vb[1];
#pragma unroll
    for (int i = 0; i < 32; i++) { l0 += h[i] * (double)vw[i]; l1 += h[i] * (double)vw[32 + i]; }
    double m = fmax(l0, l1);
    double e0 = exp(l0 - m), e1 = exp(l1 - m);
    double inv = 1.0 / (e0 + e1);
    out[320 + b * 2 + 0] = (float)(e0 * inv);
    out[320 + b * 2 + 1] = (float)(e1 * inv);
}

// ---------------- host launcher ----------------
extern "C" void kernel_launch(void* const* d_in, const int* in_sizes, int n_in,
                              void* d_out, int out_size, void* d_ws, size_t ws_size,
                              hipStream_t stream) {
    const float* x       = (const float*)d_in[0];
    const float* conv0_w = (const float*)d_in[1];
    const float* conv0_b = (const float*)d_in[2];
    const float* conv1_w = (const float*)d_in[3];
    const float* conv1_b = (const float*)d_in[4];
    const float* conv2_w = (const float*)d_in[5];
    const float* conv2_b = (const float*)d_in[6];
    const float* gn0_w   = (const float*)d_in[7];
    const float* gn0_b   = (const float*)d_in[8];
    const float* n1_w    = (const float*)d_in[9];
    const float* n1_b    = (const float*)d_in[10];
    const float* n2_w    = (const float*)d_in[11];
    const float* n2_b    = (const float*)d_in[12];
    const float* bn_g    = (const float*)d_in[13];
    const float* bn_b    = (const float*)d_in[14];
    const float* fc1_w   = (const float*)d_in[15];
    const float* fc1_b   = (const float*)d_in[16];
    const float* shape_w = (const float*)d_in[17];
    const float* shape_b = (const float*)d_in[18];
    const float* vern_w  = (const float*)d_in[19];
    const float* vern_b  = (const float*)d_in[20];
    float* out = (float*)d_out;

    // workspace: doubles first (alignment), then floats
    double* part0 = (double*)d_ws;               // 64*28*16 = 28672 doubles
    float* fbase   = (float*)(part0 + 28672);
    float* h0raw   = fbase;                      // 1605632
    float* h1      = h0raw + 1605632;            // 331776
    float* h2      = h1 + 331776;                // 663552
    float* bnscale = h2 + 663552;                // 10368
    float* bnshift = bnscale + 10368;            // 10368
    float* fc      = bnshift + 10368;            // 2048

    k_conv0<<<dim3(28, 64), dim3(128), 0, stream>>>(x, conv0_w, conv0_b, h0raw, part0);
    k_conv1_ent<<<dim3(256), dim3(1024), 0, stream>>>(h0raw, part0, gn0_w, gn0_b,
                                                      conv1_w, conv1_b, n1_w, n1_b, h1);
    k_conv2_ent<<<dim3(2048), dim3(256), 0, stream>>>(h1, conv2_w, conv2_b, n2_w, n2_b, h2);
    k_bnstats<<<dim3(162), dim3(256), 0, stream>>>(h2, bn_g, bn_b, bnscale, bnshift);
    k_fc1<<<dim3(2048), dim3(256), 0, stream>>>(h2, bnscale, bnshift, fc1_w, fc1_b, fc);
    k_heads<<<dim3(1), dim3(64), 0, stream>>>(fc, shape_w, shape_b, vern_w, vern_b, out);
}

// Round 14
// 212.477 us; speedup vs baseline: 1.1297x; 1.0184x over previous
//
#include <hip/hip_runtime.h>
#include <math.h>

#define EPSD 1e-5

// ---------------- reduction helpers ----------------

__device__ __forceinline__ double waveReduceSumD(double v) {   // result in lane 0
#pragma unroll
    for (int off = 32; off > 0; off >>= 1)
        v += __shfl_down(v, off, 64);
    return v;
}

template <int NW>
__device__ __forceinline__ double blockReduceSumD(double v, double* buf) {
    int lane = threadIdx.x & 63;
    int w = threadIdx.x >> 6;
    v = waveReduceSumD(v);
    __syncthreads();
    if (lane == 0) buf[w] = v;
    __syncthreads();
    double tot = 0.0;
#pragma unroll
    for (int i = 0; i < NW; i++) tot += buf[i];
    return tot;
}

// Build 26-entry entropy table: tab[cnt] = -(cnt/25)*log(clip(cnt/25,1e-5,1-1e-5))
__device__ __forceinline__ void build_ent_tab(float* tab) {
    int t = threadIdx.x;
    if (t < 26) {
        if (t == 0) tab[0] = 0.f;
        else {
            double pk = (double)t / 25.0;
            double cl = fmin(fmax(pk, 1e-5), 1.0 - 1e-5);
            tab[t] = (float)(-pk * log(cl));
        }
    }
}

// entropy of one 5x5 patch at (py,px) of an 18x18 channel slab in LDS.
// Division hoisted: one 25/rng per patch instead of 25 divides.
__device__ __forceinline__ float patch_ent(const float* ch, int py, int px, const float* tab) {
    float pv[25];
#pragma unroll
    for (int i = 0; i < 5; i++)
#pragma unroll
        for (int j = 0; j < 5; j++)
            pv[i * 5 + j] = ch[(py + i) * 18 + px + j];
    float mn = pv[0], mx = pv[0];
#pragma unroll
    for (int k = 1; k < 25; k++) { mn = fminf(mn, pv[k]); mx = fmaxf(mx, pv[k]); }
    float rng = (mx > mn) ? (mx - mn) : 1.0f;
    float scl = 25.0f / rng;
    unsigned long long a0 = 0ull, a1 = 0ull;
    int a2 = 0;
#pragma unroll
    for (int k = 0; k < 25; k++) {
        float tt = (pv[k] - mn) * scl;
        int bi = (int)floorf(tt);
        bi = bi < 0 ? 0 : (bi > 24 ? 24 : bi);
        unsigned sh0 = ((unsigned)(5 * bi)) & 63u;
        unsigned sh1 = ((unsigned)(5 * bi - 60)) & 63u;
        a0 += (bi < 12) ? (1ull << sh0) : 0ull;
        a1 += (bi >= 12 && bi < 24) ? (1ull << sh1) : 0ull;
        a2 += (bi == 24) ? 1 : 0;
    }
    float ent = 0.f;
#pragma unroll
    for (int k = 0; k < 12; k++) ent += tab[(a0 >> (5 * k)) & 31ull];
#pragma unroll
    for (int k = 0; k < 12; k++) ent += tab[(a1 >> (5 * k)) & 31ull];
    ent += tab[a2];
    return ent;
}

// ---------------- kA: conv0 (all 8 ch) — 2-out-row tiles, 10 KB LDS ----------------
// grid (28, 64): block = (2-out-row tile, image), 128 threads (112 conv-active).
__global__ __launch_bounds__(128, 4) void k_conv0(const float* __restrict__ x,
                                                  const float* __restrict__ w,
                                                  const float* __restrict__ bias,
                                                  float* __restrict__ h0raw,
                                                  double* __restrict__ part0) {
    __shared__ __align__(16) float tile[2508];   // 11 rows * 228 slots (one ci)
    __shared__ double redbuf[2][16];
    int tl = blockIdx.x;
    int b = blockIdx.y;
    int t = threadIdx.x;
    for (int i = t; i < 2508; i += 128) tile[i] = 0.f;
    int y_base = tl * 8 - 2;
    const float* xb = x + (size_t)b * 150528;
    float acc[8];
#pragma unroll
    for (int c = 0; c < 8; c++) acc[c] = bias[c];
    int ry = t / 56, ox = t % 56;   // used when t<112
    for (int ci = 0; ci < 3; ci++) {
        __syncthreads();   // protect tile from previous round's readers
        for (int i = t; i < 616; i += 128) {      // 11 rows * 56 float4
            int r = i / 56, f4 = i % 56;
            int yIn = y_base + r;
            if (yIn >= 0 && yIn < 224) {
                float4 v = *(const float4*)&xb[ci * 50176 + yIn * 224 + f4 * 4];
                float* tp = tile + r * 228;
                tp[114 + f4] = v.x;   // pc=4f4+2 -> slot 2*57+f4
                tp[171 + f4] = v.y;   // pc=4f4+3 -> slot 3*57+f4
                tp[f4 + 1]   = v.z;   // pc=4f4+4 -> slot 0*57+f4+1
                tp[58 + f4]  = v.w;   // pc=4f4+5 -> slot 1*57+f4+1
            }
        }
        __syncthreads();
        if (t < 112) {
            const float* wci = w + ci * 49;       // uniform -> s_load
#pragma unroll 1
            for (int ky = 0; ky < 7; ky++) {      // NOT unrolled: 56-weight batches
                const float* rp = tile + (4 * ry + ky) * 228;
#pragma unroll
                for (int kx = 0; kx < 7; kx++) {
                    float v = rp[(kx & 3) * 57 + ox + (kx >> 2)];
#pragma unroll
                    for (int c = 0; c < 8; c++)
                        acc[c] += v * wci[c * 147 + ky * 7 + kx];
                }
            }
        }
    }
    if (t < 112) {
        int oy = tl * 2 + ry;
        int opix = oy * 56 + ox;
#pragma unroll
        for (int c = 0; c < 8; c++)
            h0raw[((size_t)b * 8 + c) * 3136 + opix] = acc[c];
    } else {
#pragma unroll
        for (int c = 0; c < 8; c++) acc[c] = 0.f;   // inactive: contribute 0 to stats
    }
    int wv = t >> 6, lane = t & 63;
#pragma unroll
    for (int c = 0; c < 8; c++) {
        double rs = waveReduceSumD((double)acc[c]);
        double rq = waveReduceSumD((double)acc[c] * (double)acc[c]);
        if (lane == 0) { redbuf[wv][c * 2] = rs; redbuf[wv][c * 2 + 1] = rq; }
    }
    __syncthreads();
    if (t < 16) {
        double tot = redbuf[0][t] + redbuf[1][t];
        part0[(((size_t)b * 28 + tl) << 4) + t] = tot;   // [b][tile(28)][c*2+k]
    }
}

// ---------------- kB: conv1 (8->16, 5x5, s3, p1) + entropy-IN + ReLU ----------------
// Block = (b, group of 4 out-channels): 256 blocks, 1024 threads (16 waves).
// float4 staging (3136 % 4 == 0 -> each float4 within one channel).
__global__ __launch_bounds__(1024) void k_conv1_ent(const float* __restrict__ h0raw,
                                                    const double* __restrict__ part0,
                                                    const float* __restrict__ gw,
                                                    const float* __restrict__ gb,
                                                    const float* __restrict__ w,
                                                    const float* __restrict__ bias,
                                                    const float* __restrict__ nw,
                                                    const float* __restrict__ nb,
                                                    float* __restrict__ h1) {
    __shared__ __align__(16) float xin2[25088];   // [4 ci-pair][3136 px][2]
    __shared__ float vals[1296];    // 4 * 324
    __shared__ float tab[26];
    __shared__ float gnp[16];       // gnsc[0..7], gnsh[8..15]
    __shared__ double redbuf[16][2];
    __shared__ double entbuf[16];
    __shared__ float prm[4][3];     // mu, sc, beta per local channel
    int b = blockIdx.x >> 2;
    int grp = blockIdx.x & 3;
    int t = threadIdx.x;
    if (t < 8) {   // GN fold for input channel t of image b
        double s = 0.0, s2 = 0.0;
        const double* p = part0 + ((size_t)b * 28) * 16;
        for (int tile = 0; tile < 28; tile++) {
            s += p[tile * 16 + t * 2];
            s2 += p[tile * 16 + t * 2 + 1];
        }
        double mean = s / 3136.0;
        double var = s2 / 3136.0 - mean * mean;   // biased (GN)
        double rstd = 1.0 / sqrt(var + EPSD);
        double sc = (double)gw[t] * rstd;
        gnp[t] = (float)sc;
        gnp[8 + t] = (float)((double)gb[t] - mean * sc);
    }
    build_ent_tab(tab);
    __syncthreads();
    // float4 staging: i4 indexes float4s; 784 float4s per channel
    for (int i4 = t; i4 < 6272; i4 += 1024) {
        int ci = i4 / 784;
        int px = (i4 - ci * 784) * 4;
        float4 v4 = *(const float4*)&h0raw[(size_t)b * 25088 + ci * 3136 + px];
        float gs = gnp[ci], gh = gnp[8 + ci];
        float* dst = xin2 + (ci >> 1) * 6272 + px * 2 + (ci & 1);
        dst[0] = fmaxf(v4.x * gs + gh, 0.f);
        dst[2] = fmaxf(v4.y * gs + gh, 0.f);
        dst[4] = fmaxf(v4.z * gs + gh, 0.f);
        dst[6] = fmaxf(v4.w * gs + gh, 0.f);
    }
    __syncthreads();

    int wv = t >> 6, lane = t & 63;
    int c = wv >> 2;          // local out-channel 0..3
    int q = wv & 3;           // quarter of the 324 px
    int j_u = __builtin_amdgcn_readfirstlane(grp * 4 + c);   // SGPR channel id
    const float* wg = w + (size_t)j_u * 200;                 // uniform -> s_load
    float* vch = vals + c * 324;
    float bv = bias[j_u];
    double s = 0.0, s2 = 0.0;
    for (int p = q * 81 + lane; p < q * 81 + 81; p += 64) {
        int oy = p / 18, ox = p - oy * 18;
        int y0 = oy * 3 - 1, x0 = ox * 3 - 1;
        float acc = bv;
        if (oy >= 1 && ox >= 1) {
#pragma unroll
            for (int c2 = 0; c2 < 4; c2++) {
                const float* xp = xin2 + c2 * 6272 + (y0 * 56 + x0) * 2;
                const float* wp0 = wg + (2 * c2) * 25;
#pragma unroll
                for (int ky = 0; ky < 5; ky++)
#pragma unroll
                    for (int kx = 0; kx < 5; kx++) {
                        float2 v = *(const float2*)&xp[(ky * 56 + kx) * 2];
                        acc += v.x * wp0[ky * 5 + kx];
                        acc += v.y * wp0[25 + ky * 5 + kx];
                    }
            }
        } else {
            int ky0 = y0 < 0 ? 1 : 0;
            int kx0 = x0 < 0 ? 1 : 0;
            for (int c2 = 0; c2 < 4; c2++) {
                const float* xp = xin2 + c2 * 6272;
                const float* wp0 = wg + (2 * c2) * 25;
                for (int ky = ky0; ky < 5; ky++) {
                    for (int kx = kx0; kx < 5; kx++) {
                        float2 v = *(const float2*)&xp[((y0 + ky) * 56 + x0 + kx) * 2];
                        acc += v.x * wp0[ky * 5 + kx];
                        acc += v.y * wp0[25 + ky * 5 + kx];
                    }
                }
            }
        }
        vch[p] = acc;
        s += (double)acc; s2 += (double)acc * (double)acc;
    }
    s = waveReduceSumD(s);
    s2 = waveReduceSumD(s2);
    if (lane == 0) { redbuf[wv][0] = s; redbuf[wv][1] = s2; }
    __syncthreads();   // vals complete + stats partials visible
    double ent = 0.0;
    if (lane < 49) {
        int pi = q * 49 + lane;
        ent = (double)patch_ent(vch, pi / 14, pi % 14, tab);
    }
    ent = waveReduceSumD(ent);
    if (lane == 0) entbuf[wv] = ent;
    __syncthreads();
    if (t < 4) {
        double ss = 0.0, qq = 0.0, ee = 0.0;
        for (int k = 0; k < 4; k++) {
            ss += redbuf[t * 4 + k][0];
            qq += redbuf[t * 4 + k][1];
            ee += entbuf[t * 4 + k];
        }
        double entmean = ee / 196.0;
        double mean = ss / 324.0;
        double varb = qq / 324.0 - mean * mean;
        double varu = varb * (324.0 / 323.0);   // unbiased (torch default)
        double rstd = 1.0 / sqrt(varu + EPSD);
        prm[t][0] = (float)mean;
        prm[t][1] = (float)((double)nw[grp * 4 + t] * entmean * rstd);
        prm[t][2] = nb[grp * 4 + t];
    }
    __syncthreads();
    float* outp = h1 + ((size_t)b * 16 + grp * 4) * 324;
    for (int i = t; i < 1296; i += 1024) {
        int cc = i / 324;
        outp[i] = fmaxf((vals[i] - prm[cc][0]) * prm[cc][1] + prm[cc][2], 0.f);
    }
}

// ---------------- kC: conv2 (16->32, 3x3, s1, p1) + entropy-IN + ReLU ----------------
// One block per (b, c): 2048 blocks, 256 threads. float4 staging (324 % 4 == 0).
__global__ __launch_bounds__(256) void k_conv2_ent(const float* __restrict__ in,
                                                   const float* __restrict__ w,
                                                   const float* __restrict__ bias,
                                                   const float* __restrict__ nw,
                                                   const float* __restrict__ nb,
                                                   float* __restrict__ out) {
    __shared__ __align__(16) float xin2[5184];   // [8 pair][324 px][2]
    __shared__ float vals[324];
    __shared__ float tab[26];
    __shared__ double rbuf[4];
    int b = blockIdx.x >> 5;
    int c = blockIdx.x & 31;      // uniform
    int t = threadIdx.x;
    const float* xb = in + (size_t)b * 5184;
    for (int i4 = t; i4 < 1296; i4 += 256) {   // 81 float4s per channel
        int ci = i4 / 81;
        int px = (i4 - ci * 81) * 4;
        float4 v4 = *(const float4*)&xb[ci * 324 + px];
        float* dst = xin2 + (ci >> 1) * 648 + px * 2 + (ci & 1);
        dst[0] = v4.x; dst[2] = v4.y; dst[4] = v4.z; dst[6] = v4.w;
    }
    build_ent_tab(tab);
    __syncthreads();
    const float* wc = w + c * 144;    // uniform base -> s_load on unrolled indices
    float bv = bias[c];
    double s = 0.0, s2 = 0.0;
    {   // interior: 256 px, one per thread
        int oy = 1 + (t >> 4), ox = 1 + (t & 15);
        int base = ((oy - 1) * 18 + (ox - 1)) * 2;
        float acc = bv;
#pragma unroll
        for (int c2 = 0; c2 < 8; c2++) {
            const float* xp = xin2 + c2 * 648 + base;
            const float* wp = wc + c2 * 18;
#pragma unroll
            for (int ky = 0; ky < 3; ky++)
#pragma unroll
                for (int kx = 0; kx < 3; kx++) {
                    float2 v = *(const float2*)&xp[(ky * 18 + kx) * 2];
                    acc += v.x * wp[ky * 3 + kx];
                    acc += v.y * wp[9 + ky * 3 + kx];
                }
        }
        vals[oy * 18 + ox] = acc;
        s += (double)acc; s2 += (double)acc * (double)acc;
    }
    if (t < 68) {   // boundary px
        int oy, ox;
        if (t < 18)      { oy = 0;      ox = t; }
        else if (t < 36) { oy = 17;     ox = t - 18; }
        else if (t < 52) { oy = t - 35; ox = 0; }
        else             { oy = t - 51; ox = 17; }
        int y0 = oy - 1, x0 = ox - 1;
        int ky0 = y0 < 0 ? 1 : 0;
        int ky1 = (18 - y0) < 3 ? 2 : 3;
        int kx0 = x0 < 0 ? 1 : 0;
        int kx1 = (18 - x0) < 3 ? 2 : 3;
        float acc = bv;
        for (int c2 = 0; c2 < 8; c2++) {
            const float* xp = xin2 + c2 * 648;
            const float* wp = wc + c2 * 18;
            for (int ky = ky0; ky < ky1; ky++) {
                for (int kx = kx0; kx < kx1; kx++) {
                    float2 v = *(const float2*)&xp[((y0 + ky) * 18 + x0 + kx) * 2];
                    acc += v.x * wp[ky * 3 + kx];
                    acc += v.y * wp[9 + ky * 3 + kx];
                }
            }
        }
        vals[oy * 18 + ox] = acc;
        s += (double)acc; s2 += (double)acc * (double)acc;
    }
    __syncthreads();
    double ent = 0.0;
    if (t < 196) ent = (double)patch_ent(vals, t / 14, t % 14, tab);
    double entmean = blockReduceSumD<4>(ent, rbuf) / 196.0;
    double ssum  = blockReduceSumD<4>(s, rbuf);
    double s2sum = blockReduceSumD<4>(s2, rbuf);
    double mean = ssum / 324.0;
    double varb = s2sum / 324.0 - mean * mean;
    double varu = varb * (324.0 / 323.0);
    double rstd = 1.0 / sqrt(varu + EPSD);
    float sc = (float)((double)nw[c] * entmean * rstd);
    float mu = (float)mean;
    float be = nb[c];
    float* outp = out + ((size_t)b * 32 + c) * 324;
    for (int idx = t; idx < 324; idx += 256)
        outp[idx] = fmaxf((vals[idx] - mu) * sc + be, 0.f);
}

// ---------------- kD: BN stats -> scale/shift AND hv = h2*scale+shift ----------------
// 162 blocks, 4-way batch split. Writing hv here halves k_fc1's streamed bytes.
__global__ __launch_bounds__(256) void k_bnstats(const float* __restrict__ h2,
                                                 const float* __restrict__ g,
                                                 const float* __restrict__ bb,
                                                 float* __restrict__ hv) {
    __shared__ double sb[4][64], qb[4][64];
    __shared__ float scsh[2][64];
    int lane = threadIdx.x & 63;
    int q = threadIdx.x >> 6;
    int f = blockIdx.x * 64 + lane;
    double s = 0.0, s2 = 0.0;
    for (int b = q * 16; b < q * 16 + 16; b++) {
        double v = (double)h2[(size_t)b * 10368 + f];
        s += v; s2 += v * v;
    }
    sb[q][lane] = s; qb[q][lane] = s2;
    __syncthreads();
    if (threadIdx.x < 64) {
        double S = sb[0][lane] + sb[1][lane] + sb[2][lane] + sb[3][lane];
        double Q = qb[0][lane] + qb[1][lane] + qb[2][lane] + qb[3][lane];
        double mean = S / 64.0;
        double var = Q / 64.0 - mean * mean;   // biased (BN training)
        double rstd = 1.0 / sqrt(var + EPSD);
        double sc = (double)g[f] * rstd;
        scsh[0][lane] = (float)sc;
        scsh[1][lane] = (float)((double)bb[f] - mean * sc);
    }
    __syncthreads();
    float sc = scsh[0][lane], sh = scsh[1][lane];
    for (int b = q * 16; b < q * 16 + 16; b++)
        hv[(size_t)b * 10368 + f] = h2[(size_t)b * 10368 + f] * sc + sh;
}

// ---------------- kE: fc1 on precomputed hv, + ReLU (float4, 2 streams) ----------------
__global__ __launch_bounds__(256) void k_fc1(const float* __restrict__ hv,
                                             const float* __restrict__ w1,
                                             const float* __restrict__ b1,
                                             float* __restrict__ fcout) {
    __shared__ double rbuf[4];
    int b = blockIdx.x >> 5;
    int j = blockIdx.x & 31;
    const float* hb = hv + (size_t)b * 10368;
    const float* wj = w1 + (size_t)j * 10368;
    double acc = 0.0;
    for (int f = threadIdx.x * 4; f < 10368; f += 1024) {
        float4 h4 = *(const float4*)&hb[f];
        float4 w4 = *(const float4*)&wj[f];
        acc += (double)(h4.x * w4.x);
        acc += (double)(h4.y * w4.y);
        acc += (double)(h4.z * w4.z);
        acc += (double)(h4.w * w4.w);
    }
    acc = blockReduceSumD<4>(acc, rbuf);
    if (threadIdx.x == 0)
        fcout[b * 32 + j] = (float)fmax(acc + (double)b1[j], 0.0);
}

// ---------------- kF: heads + softmax ----------------
__global__ __launch_bounds__(64) void k_heads(const float* __restrict__ fc,
                                              const float* __restrict__ sw,
                                              const float* __restrict__ sb,
                                              const float* __restrict__ vw,
                                              const float* __restrict__ vb,
                                              float* __restrict__ out) {
    int b = threadIdx.x;
    double h[32];
#pragma unroll
    for (int i = 0; i < 32; i++) h[i] = (double)fc[b * 32 + i];
    double lg[5];
    double mx = -1e300;
#pragma unroll
    for (int k = 0; k < 5; k++) {
        double a = (double)sb[k];
#pragma unroll
        for (int i = 0; i < 32; i++) a += h[i] * (double)sw[k * 32 + i];
        lg[k] = a;
        mx = fmax(mx, a);
    }
    double se = 0.0;
#pragma unroll
    for (int k = 0; k < 5; k++) { lg[k] = exp(lg[k] - mx); se += lg[k]; }
#pragma unroll
    for (int k = 0; k < 5; k++) out[b * 5 + k] = (float)(lg[k] / se);
    double l0 = (double)vb[0], l1 = (double)vb[1];
#pragma unroll
    for (int i = 0; i < 32; i++) { l0 += h[i] * (double)vw[i]; l1 += h[i] * (double)vw[32 + i]; }
    double m = fmax(l0, l1);
    double e0 = exp(l0 - m), e1 = exp(l1 - m);
    double inv = 1.0 / (e0 + e1);
    out[320 + b * 2 + 0] = (float)(e0 * inv);
    out[320 + b * 2 + 1] = (float)(e1 * inv);
}

// ---------------- host launcher ----------------
extern "C" void kernel_launch(void* const* d_in, const int* in_sizes, int n_in,
                              void* d_out, int out_size, void* d_ws, size_t ws_size,
                              hipStream_t stream) {
    const float* x       = (const float*)d_in[0];
    const float* conv0_w = (const float*)d_in[1];
    const float* conv0_b = (const float*)d_in[2];
    const float* conv1_w = (const float*)d_in[3];
    const float* conv1_b = (const float*)d_in[4];
    const float* conv2_w = (const float*)d_in[5];
    const float* conv2_b = (const float*)d_in[6];
    const float* gn0_w   = (const float*)d_in[7];
    const float* gn0_b   = (const float*)d_in[8];
    const float* n1_w    = (const float*)d_in[9];
    const float* n1_b    = (const float*)d_in[10];
    const float* n2_w    = (const float*)d_in[11];
    const float* n2_b    = (const float*)d_in[12];
    const float* bn_g    = (const float*)d_in[13];
    const float* bn_b    = (const float*)d_in[14];
    const float* fc1_w   = (const float*)d_in[15];
    const float* fc1_b   = (const float*)d_in[16];
    const float* shape_w = (const float*)d_in[17];
    const float* shape_b = (const float*)d_in[18];
    const float* vern_w  = (const float*)d_in[19];
    const float* vern_b  = (const float*)d_in[20];
    float* out = (float*)d_out;

    // workspace: doubles first (alignment), then floats
    double* part0 = (double*)d_ws;               // 64*28*16 = 28672 doubles
    float* fbase   = (float*)(part0 + 28672);
    float* h0raw   = fbase;                      // 1605632
    float* h1      = h0raw + 1605632;            // 331776
    float* h2      = h1 + 331776;                // 663552
    float* hv      = h2 + 663552;                // 663552
    float* fc      = hv + 663552;                // 2048

    k_conv0<<<dim3(28, 64), dim3(128), 0, stream>>>(x, conv0_w, conv0_b, h0raw, part0);
    k_conv1_ent<<<dim3(256), dim3(1024), 0, stream>>>(h0raw, part0, gn0_w, gn0_b,
                                                      conv1_w, conv1_b, n1_w, n1_b, h1);
    k_conv2_ent<<<dim3(2048), dim3(256), 0, stream>>>(h1, conv2_w, conv2_b, n2_w, n2_b, h2);
    k_bnstats<<<dim3(162), dim3(256), 0, stream>>>(h2, bn_g, bn_b, hv);
    k_fc1<<<dim3(2048), dim3(256), 0, stream>>>(hv, fc1_w, fc1_b, fc);
    k_heads<<<dim3(1), dim3(64), 0, stream>>>(fc, shape_w, shape_b, vern_w, vern_b, out);
}

// Round 15
// 210.836 us; speedup vs baseline: 1.1385x; 1.0078x over previous
//
#include <hip/hip_runtime.h>
#include <math.h>

#define EPSD 1e-5

// ---------------- reduction helpers ----------------

__device__ __forceinline__ double waveReduceSumD(double v) {   // result in lane 0
#pragma unroll
    for (int off = 32; off > 0; off >>= 1)
        v += __shfl_down(v, off, 64);
    return v;
}

template <int NW>
__device__ __forceinline__ double blockReduceSumD(double v, double* buf) {
    int lane = threadIdx.x & 63;
    int w = threadIdx.x >> 6;
    v = waveReduceSumD(v);
    __syncthreads();
    if (lane == 0) buf[w] = v;
    __syncthreads();
    double tot = 0.0;
#pragma unroll
    for (int i = 0; i < NW; i++) tot += buf[i];
    return tot;
}

// Build 26-entry entropy table: tab[cnt] = -(cnt/25)*log(clip(cnt/25,1e-5,1-1e-5))
__device__ __forceinline__ void build_ent_tab(float* tab) {
    int t = threadIdx.x;
    if (t < 26) {
        if (t == 0) tab[0] = 0.f;
        else {
            double pk = (double)t / 25.0;
            double cl = fmin(fmax(pk, 1e-5), 1.0 - 1e-5);
            tab[t] = (float)(-pk * log(cl));
        }
    }
}

// entropy of one 5x5 patch at (py,px) of an 18x18 channel slab in LDS.
// Division hoisted: one 25/rng per patch instead of 25 divides.
__device__ __forceinline__ float patch_ent(const float* ch, int py, int px, const float* tab) {
    float pv[25];
#pragma unroll
    for (int i = 0; i < 5; i++)
#pragma unroll
        for (int j = 0; j < 5; j++)
            pv[i * 5 + j] = ch[(py + i) * 18 + px + j];
    float mn = pv[0], mx = pv[0];
#pragma unroll
    for (int k = 1; k < 25; k++) { mn = fminf(mn, pv[k]); mx = fmaxf(mx, pv[k]); }
    float rng = (mx > mn) ? (mx - mn) : 1.0f;
    float scl = 25.0f / rng;
    unsigned long long a0 = 0ull, a1 = 0ull;
    int a2 = 0;
#pragma unroll
    for (int k = 0; k < 25; k++) {
        float tt = (pv[k] - mn) * scl;
        int bi = (int)floorf(tt);
        bi = bi < 0 ? 0 : (bi > 24 ? 24 : bi);
        unsigned sh0 = ((unsigned)(5 * bi)) & 63u;
        unsigned sh1 = ((unsigned)(5 * bi - 60)) & 63u;
        a0 += (bi < 12) ? (1ull << sh0) : 0ull;
        a1 += (bi >= 12 && bi < 24) ? (1ull << sh1) : 0ull;
        a2 += (bi == 24) ? 1 : 0;
    }
    float ent = 0.f;
#pragma unroll
    for (int k = 0; k < 12; k++) ent += tab[(a0 >> (5 * k)) & 31ull];
#pragma unroll
    for (int k = 0; k < 12; k++) ent += tab[(a1 >> (5 * k)) & 31ull];
    ent += tab[a2];
    return ent;
}

// ---------------- kA: conv0 (all 8 ch) — 2-out-row tiles, 10 KB LDS ----------------
// grid (28, 64): block = (2-out-row tile, image), 128 threads (112 conv-active).
__global__ __launch_bounds__(128, 4) void k_conv0(const float* __restrict__ x,
                                                  const float* __restrict__ w,
                                                  const float* __restrict__ bias,
                                                  float* __restrict__ h0raw,
                                                  double* __restrict__ part0) {
    __shared__ __align__(16) float tile[2508];   // 11 rows * 228 slots (one ci)
    __shared__ double redbuf[2][16];
    int tl = blockIdx.x;
    int b = blockIdx.y;
    int t = threadIdx.x;
    for (int i = t; i < 2508; i += 128) tile[i] = 0.f;
    int y_base = tl * 8 - 2;
    const float* xb = x + (size_t)b * 150528;
    float acc[8];
#pragma unroll
    for (int c = 0; c < 8; c++) acc[c] = bias[c];
    int ry = t / 56, ox = t % 56;   // used when t<112
    for (int ci = 0; ci < 3; ci++) {
        __syncthreads();   // protect tile from previous round's readers
        for (int i = t; i < 616; i += 128) {      // 11 rows * 56 float4
            int r = i / 56, f4 = i % 56;
            int yIn = y_base + r;
            if (yIn >= 0 && yIn < 224) {
                float4 v = *(const float4*)&xb[ci * 50176 + yIn * 224 + f4 * 4];
                float* tp = tile + r * 228;
                tp[114 + f4] = v.x;   // pc=4f4+2 -> slot 2*57+f4
                tp[171 + f4] = v.y;   // pc=4f4+3 -> slot 3*57+f4
                tp[f4 + 1]   = v.z;   // pc=4f4+4 -> slot 0*57+f4+1
                tp[58 + f4]  = v.w;   // pc=4f4+5 -> slot 1*57+f4+1
            }
        }
        __syncthreads();
        if (t < 112) {
            const float* wci = w + ci * 49;       // uniform -> s_load
#pragma unroll 1
            for (int ky = 0; ky < 7; ky++) {      // NOT unrolled: 56-weight batches
                const float* rp = tile + (4 * ry + ky) * 228;
#pragma unroll
                for (int kx = 0; kx < 7; kx++) {
                    float v = rp[(kx & 3) * 57 + ox + (kx >> 2)];
#pragma unroll
                    for (int c = 0; c < 8; c++)
                        acc[c] += v * wci[c * 147 + ky * 7 + kx];
                }
            }
        }
    }
    if (t < 112) {
        int oy = tl * 2 + ry;
        int opix = oy * 56 + ox;
#pragma unroll
        for (int c = 0; c < 8; c++)
            h0raw[((size_t)b * 8 + c) * 3136 + opix] = acc[c];
    } else {
#pragma unroll
        for (int c = 0; c < 8; c++) acc[c] = 0.f;   // inactive: contribute 0 to stats
    }
    int wv = t >> 6, lane = t & 63;
#pragma unroll
    for (int c = 0; c < 8; c++) {
        double rs = waveReduceSumD((double)acc[c]);
        double rq = waveReduceSumD((double)acc[c] * (double)acc[c]);
        if (lane == 0) { redbuf[wv][c * 2] = rs; redbuf[wv][c * 2 + 1] = rq; }
    }
    __syncthreads();
    if (t < 16) {
        double tot = redbuf[0][t] + redbuf[1][t];
        part0[(((size_t)b * 28 + tl) << 4) + t] = tot;   // [b][tile(28)][c*2+k]
    }
}

// ---------------- kB: conv1 (8->16, 5x5, s3, p1) + entropy-IN + ReLU ----------------
// Block = (b, group of 4 out-channels): 256 blocks, 1024 threads (16 waves).
__global__ __launch_bounds__(1024) void k_conv1_ent(const float* __restrict__ h0raw,
                                                    const double* __restrict__ part0,
                                                    const float* __restrict__ gw,
                                                    const float* __restrict__ gb,
                                                    const float* __restrict__ w,
                                                    const float* __restrict__ bias,
                                                    const float* __restrict__ nw,
                                                    const float* __restrict__ nb,
                                                    float* __restrict__ h1) {
    __shared__ __align__(16) float xin2[25088];   // [4 ci-pair][3136 px][2]
    __shared__ float vals[1296];    // 4 * 324
    __shared__ float tab[26];
    __shared__ float gnp[16];       // gnsc[0..7], gnsh[8..15]
    __shared__ double redbuf[16][2];
    __shared__ double entbuf[16];
    __shared__ float prm[4][3];     // mu, sc, beta per local channel
    int b = blockIdx.x >> 2;
    int grp = blockIdx.x & 3;
    int t = threadIdx.x;
    if (t < 8) {   // GN fold for input channel t of image b
        double s = 0.0, s2 = 0.0;
        const double* p = part0 + ((size_t)b * 28) * 16;
        for (int tile = 0; tile < 28; tile++) {
            s += p[tile * 16 + t * 2];
            s2 += p[tile * 16 + t * 2 + 1];
        }
        double mean = s / 3136.0;
        double var = s2 / 3136.0 - mean * mean;   // biased (GN)
        double rstd = 1.0 / sqrt(var + EPSD);
        double sc = (double)gw[t] * rstd;
        gnp[t] = (float)sc;
        gnp[8 + t] = (float)((double)gb[t] - mean * sc);
    }
    build_ent_tab(tab);
    __syncthreads();
    // float4 staging: i4 indexes float4s; 784 float4s per channel
    for (int i4 = t; i4 < 6272; i4 += 1024) {
        int ci = i4 / 784;
        int px = (i4 - ci * 784) * 4;
        float4 v4 = *(const float4*)&h0raw[(size_t)b * 25088 + ci * 3136 + px];
        float gs = gnp[ci], gh = gnp[8 + ci];
        float* dst = xin2 + (ci >> 1) * 6272 + px * 2 + (ci & 1);
        dst[0] = fmaxf(v4.x * gs + gh, 0.f);
        dst[2] = fmaxf(v4.y * gs + gh, 0.f);
        dst[4] = fmaxf(v4.z * gs + gh, 0.f);
        dst[6] = fmaxf(v4.w * gs + gh, 0.f);
    }
    __syncthreads();

    int wv = t >> 6, lane = t & 63;
    int c = wv >> 2;          // local out-channel 0..3
    int q = wv & 3;           // quarter of the 324 px
    int j_u = __builtin_amdgcn_readfirstlane(grp * 4 + c);   // SGPR channel id
    const float* wg = w + (size_t)j_u * 200;                 // uniform -> s_load
    float* vch = vals + c * 324;
    float bv = bias[j_u];
    double s = 0.0, s2 = 0.0;
    for (int p = q * 81 + lane; p < q * 81 + 81; p += 64) {
        int oy = p / 18, ox = p - oy * 18;
        int y0 = oy * 3 - 1, x0 = ox * 3 - 1;
        float acc = bv;
        if (oy >= 1 && ox >= 1) {
#pragma unroll
            for (int c2 = 0; c2 < 4; c2++) {
                const float* xp = xin2 + c2 * 6272 + (y0 * 56 + x0) * 2;
                const float* wp0 = wg + (2 * c2) * 25;
#pragma unroll
                for (int ky = 0; ky < 5; ky++)
#pragma unroll
                    for (int kx = 0; kx < 5; kx++) {
                        float2 v = *(const float2*)&xp[(ky * 56 + kx) * 2];
                        acc += v.x * wp0[ky * 5 + kx];
                        acc += v.y * wp0[25 + ky * 5 + kx];
                    }
            }
        } else {
            int ky0 = y0 < 0 ? 1 : 0;
            int kx0 = x0 < 0 ? 1 : 0;
            for (int c2 = 0; c2 < 4; c2++) {
                const float* xp = xin2 + c2 * 6272;
                const float* wp0 = wg + (2 * c2) * 25;
                for (int ky = ky0; ky < 5; ky++) {
                    for (int kx = kx0; kx < 5; kx++) {
                        float2 v = *(const float2*)&xp[((y0 + ky) * 56 + x0 + kx) * 2];
                        acc += v.x * wp0[ky * 5 + kx];
                        acc += v.y * wp0[25 + ky * 5 + kx];
                    }
                }
            }
        }
        vch[p] = acc;
        s += (double)acc; s2 += (double)acc * (double)acc;
    }
    s = waveReduceSumD(s);
    s2 = waveReduceSumD(s2);
    if (lane == 0) { redbuf[wv][0] = s; redbuf[wv][1] = s2; }
    __syncthreads();   // vals complete + stats partials visible
    double ent = 0.0;
    if (lane < 49) {
        int pi = q * 49 + lane;
        ent = (double)patch_ent(vch, pi / 14, pi % 14, tab);
    }
    ent = waveReduceSumD(ent);
    if (lane == 0) entbuf[wv] = ent;
    __syncthreads();
    if (t < 4) {
        double ss = 0.0, qq = 0.0, ee = 0.0;
        for (int k = 0; k < 4; k++) {
            ss += redbuf[t * 4 + k][0];
            qq += redbuf[t * 4 + k][1];
            ee += entbuf[t * 4 + k];
        }
        double entmean = ee / 196.0;
        double mean = ss / 324.0;
        double varb = qq / 324.0 - mean * mean;
        double varu = varb * (324.0 / 323.0);   // unbiased (torch default)
        double rstd = 1.0 / sqrt(varu + EPSD);
        prm[t][0] = (float)mean;
        prm[t][1] = (float)((double)nw[grp * 4 + t] * entmean * rstd);
        prm[t][2] = nb[grp * 4 + t];
    }
    __syncthreads();
    float* outp = h1 + ((size_t)b * 16 + grp * 4) * 324;
    for (int i = t; i < 1296; i += 1024) {
        int cc = i / 324;
        outp[i] = fmaxf((vals[i] - prm[cc][0]) * prm[cc][1] + prm[cc][2], 0.f);
    }
}

// ---------------- kC: conv2 (16->32, 3x3, s1, p1) + entropy-IN + ReLU ----------------
// Block = (b, pair of out-channels): 1024 blocks, 512 threads (4 blocks/CU).
// Taps and staging shared by both channels; entropy fully parallel:
// threads 0..195 -> ch0 patches, 256..451 -> ch1 patches.
__global__ __launch_bounds__(512) void k_conv2_ent(const float* __restrict__ in,
                                                   const float* __restrict__ w,
                                                   const float* __restrict__ bias,
                                                   const float* __restrict__ nw,
                                                   const float* __restrict__ nb,
                                                   float* __restrict__ out) {
    __shared__ __align__(16) float xin2[5184];   // [8 in-pair][324 px][2]
    __shared__ float vals[648];     // [2 out-ch][324]
    __shared__ float tab[26];
    __shared__ double redbuf[8][4]; // per-wave s0,q0,s1,q1
    __shared__ double entbuf[8];
    __shared__ float prm[2][3];     // mu, sc, beta per channel
    int b = blockIdx.x >> 4;
    int pr = blockIdx.x & 15;       // uniform
    int c0 = pr * 2, c1 = c0 + 1;
    int t = threadIdx.x;
    const float* xb = in + (size_t)b * 5184;
    for (int i4 = t; i4 < 1296; i4 += 512) {   // 81 float4s per input channel
        int ci = i4 / 81;
        int px = (i4 - ci * 81) * 4;
        float4 v4 = *(const float4*)&xb[ci * 324 + px];
        float* dst = xin2 + (ci >> 1) * 648 + px * 2 + (ci & 1);
        dst[0] = v4.x; dst[2] = v4.y; dst[4] = v4.z; dst[6] = v4.w;
    }
    build_ent_tab(tab);
    __syncthreads();
    const float* wc0 = w + c0 * 144;   // uniform -> s_load
    const float* wc1 = w + c1 * 144;
    float acc0 = 0.f, acc1 = 0.f;
    if (t < 256) {   // interior: 256 px, one per thread, guard-free
        int oy = 1 + (t >> 4), ox = 1 + (t & 15);
        int base = ((oy - 1) * 18 + (ox - 1)) * 2;
        acc0 = bias[c0]; acc1 = bias[c1];
#pragma unroll
        for (int c2 = 0; c2 < 8; c2++) {
            const float* xp = xin2 + c2 * 648 + base;
            const float* wp0 = wc0 + c2 * 18;
            const float* wp1 = wc1 + c2 * 18;
#pragma unroll
            for (int ky = 0; ky < 3; ky++)
#pragma unroll
                for (int kx = 0; kx < 3; kx++) {
                    float2 v = *(const float2*)&xp[(ky * 18 + kx) * 2];
                    acc0 += v.x * wp0[ky * 3 + kx];
                    acc0 += v.y * wp0[9 + ky * 3 + kx];
                    acc1 += v.x * wp1[ky * 3 + kx];
                    acc1 += v.y * wp1[9 + ky * 3 + kx];
                }
        }
        vals[oy * 18 + ox] = acc0;
        vals[324 + oy * 18 + ox] = acc1;
    } else if (t < 324) {   // 68 boundary px on threads 256..323
        int bid = t - 256;
        int oy, ox;
        if (bid < 18)      { oy = 0;        ox = bid; }
        else if (bid < 36) { oy = 17;       ox = bid - 18; }
        else if (bid < 52) { oy = bid - 35; ox = 0; }
        else               { oy = bid - 51; ox = 17; }
        int y0 = oy - 1, x0 = ox - 1;
        int ky0 = y0 < 0 ? 1 : 0;
        int ky1 = (18 - y0) < 3 ? 2 : 3;
        int kx0 = x0 < 0 ? 1 : 0;
        int kx1 = (18 - x0) < 3 ? 2 : 3;
        acc0 = bias[c0]; acc1 = bias[c1];
        for (int c2 = 0; c2 < 8; c2++) {
            const float* xp = xin2 + c2 * 648;
            const float* wp0 = wc0 + c2 * 18;
            const float* wp1 = wc1 + c2 * 18;
            for (int ky = ky0; ky < ky1; ky++) {
                for (int kx = kx0; kx < kx1; kx++) {
                    float2 v = *(const float2*)&xp[((y0 + ky) * 18 + x0 + kx) * 2];
                    acc0 += v.x * wp0[ky * 3 + kx];
                    acc0 += v.y * wp0[9 + ky * 3 + kx];
                    acc1 += v.x * wp1[ky * 3 + kx];
                    acc1 += v.y * wp1[9 + ky * 3 + kx];
                }
            }
        }
        vals[oy * 18 + ox] = acc0;
        vals[324 + oy * 18 + ox] = acc1;
    }
    // stats: every thread contributes (0 if inactive)
    int wv = t >> 6, lane = t & 63;
    {
        double s0 = waveReduceSumD((double)acc0);
        double q0 = waveReduceSumD((double)acc0 * (double)acc0);
        double s1 = waveReduceSumD((double)acc1);
        double q1 = waveReduceSumD((double)acc1 * (double)acc1);
        if (lane == 0) {
            redbuf[wv][0] = s0; redbuf[wv][1] = q0;
            redbuf[wv][2] = s1; redbuf[wv][3] = q1;
        }
    }
    __syncthreads();   // vals complete
    // entropy: threads 0..195 ch0, 256..451 ch1
    double ent = 0.0;
    if (t < 196) ent = (double)patch_ent(vals, t / 14, t % 14, tab);
    else if (t >= 256 && t < 452) {
        int pi = t - 256;
        ent = (double)patch_ent(vals + 324, pi / 14, pi % 14, tab);
    }
    ent = waveReduceSumD(ent);
    if (lane == 0) entbuf[wv] = ent;
    __syncthreads();
    if (t < 2) {   // channel t finalize
        double ss = 0.0, qq = 0.0, ee = 0.0;
        for (int k = 0; k < 8; k++) {
            ss += redbuf[k][t * 2];
            qq += redbuf[k][t * 2 + 1];
        }
        // ent: waves 0-3 hold ch0, waves 4-7 hold ch1
        for (int k = 0; k < 4; k++) ee += entbuf[t * 4 + k];
        double entmean = ee / 196.0;
        double mean = ss / 324.0;
        double varb = qq / 324.0 - mean * mean;
        double varu = varb * (324.0 / 323.0);
        double rstd = 1.0 / sqrt(varu + EPSD);
        prm[t][0] = (float)mean;
        prm[t][1] = (float)((double)nw[c0 + t] * entmean * rstd);
        prm[t][2] = nb[c0 + t];
    }
    __syncthreads();
    float* outp = out + ((size_t)b * 32 + c0) * 324;
    for (int i = t; i < 648; i += 512) {
        int cc = i / 324;
        outp[i] = fmaxf((vals[i] - prm[cc][0]) * prm[cc][1] + prm[cc][2], 0.f);
    }
}

// ---------------- kD: BN stats -> scale/shift AND hv = h2*scale+shift ----------------
// 162 blocks, 4-way batch split. Writing hv here halves k_fc1's streamed bytes.
__global__ __launch_bounds__(256) void k_bnstats(const float* __restrict__ h2,
                                                 const float* __restrict__ g,
                                                 const float* __restrict__ bb,
                                                 float* __restrict__ hv) {
    __shared__ double sb[4][64], qb[4][64];
    __shared__ float scsh[2][64];
    int lane = threadIdx.x & 63;
    int q = threadIdx.x >> 6;
    int f = blockIdx.x * 64 + lane;
    double s = 0.0, s2 = 0.0;
    for (int b = q * 16; b < q * 16 + 16; b++) {
        double v = (double)h2[(size_t)b * 10368 + f];
        s += v; s2 += v * v;
    }
    sb[q][lane] = s; qb[q][lane] = s2;
    __syncthreads();
    if (threadIdx.x < 64) {
        double S = sb[0][lane] + sb[1][lane] + sb[2][lane] + sb[3][lane];
        double Q = qb[0][lane] + qb[1][lane] + qb[2][lane] + qb[3][lane];
        double mean = S / 64.0;
        double var = Q / 64.0 - mean * mean;   // biased (BN training)
        double rstd = 1.0 / sqrt(var + EPSD);
        double sc = (double)g[f] * rstd;
        scsh[0][lane] = (float)sc;
        scsh[1][lane] = (float)((double)bb[f] - mean * sc);
    }
    __syncthreads();
    float sc = scsh[0][lane], sh = scsh[1][lane];
    for (int b = q * 16; b < q * 16 + 16; b++)
        hv[(size_t)b * 10368 + f] = h2[(size_t)b * 10368 + f] * sc + sh;
}

// ---------------- kE: fc1 on precomputed hv, + ReLU (float4, 2 streams) ----------------
__global__ __launch_bounds__(256) void k_fc1(const float* __restrict__ hv,
                                             const float* __restrict__ w1,
                                             const float* __restrict__ b1,
                                             float* __restrict__ fcout) {
    __shared__ double rbuf[4];
    int b = blockIdx.x >> 5;
    int j = blockIdx.x & 31;
    const float* hb = hv + (size_t)b * 10368;
    const float* wj = w1 + (size_t)j * 10368;
    double acc = 0.0;
    for (int f = threadIdx.x * 4; f < 10368; f += 1024) {
        float4 h4 = *(const float4*)&hb[f];
        float4 w4 = *(const float4*)&wj[f];
        acc += (double)(h4.x * w4.x);
        acc += (double)(h4.y * w4.y);
        acc += (double)(h4.z * w4.z);
        acc += (double)(h4.w * w4.w);
    }
    acc = blockReduceSumD<4>(acc, rbuf);
    if (threadIdx.x == 0)
        fcout[b * 32 + j] = (float)fmax(acc + (double)b1[j], 0.0);
}

// ---------------- kF: heads + softmax ----------------
__global__ __launch_bounds__(64) void k_heads(const float* __restrict__ fc,
                                              const float* __restrict__ sw,
                                              const float* __restrict__ sb,
                                              const float* __restrict__ vw,
                                              const float* __restrict__ vb,
                                              float* __restrict__ out) {
    int b = threadIdx.x;
    double h[32];
#pragma unroll
    for (int i = 0; i < 32; i++) h[i] = (double)fc[b * 32 + i];
    double lg[5];
    double mx = -1e300;
#pragma unroll
    for (int k = 0; k < 5; k++) {
        double a = (double)sb[k];
#pragma unroll
        for (int i = 0; i < 32; i++) a += h[i] * (double)sw[k * 32 + i];
        lg[k] = a;
        mx = fmax(mx, a);
    }
    double se = 0.0;
#pragma unroll
    for (int k = 0; k < 5; k++) { lg[k] = exp(lg[k] - mx); se += lg[k]; }
#pragma unroll
    for (int k = 0; k < 5; k++) out[b * 5 + k] = (float)(lg[k] / se);
    double l0 = (double)vb[0], l1 = (double)vb[1];
#pragma unroll
    for (int i = 0; i < 32; i++) { l0 += h[i] * (double)vw[i]; l1 += h[i] * (double)vw[32 + i]; }
    double m = fmax(l0, l1);
    double e0 = exp(l0 - m), e1 = exp(l1 - m);
    double inv = 1.0 / (e0 + e1);
    out[320 + b * 2 + 0] = (float)(e0 * inv);
    out[320 + b * 2 + 1] = (float)(e1 * inv);
}

// ---------------- host launcher ----------------
extern "C" void kernel_launch(void* const* d_in, const int* in_sizes, int n_in,
                              void* d_out, int out_size, void* d_ws, size_t ws_size,
                              hipStream_t stream) {
    const float* x       = (const float*)d_in[0];
    const float* conv0_w = (const float*)d_in[1];
    const float* conv0_b = (const float*)d_in[2];
    const float* conv1_w = (const float*)d_in[3];
    const float* conv1_b = (const float*)d_in[4];
    const float* conv2_w = (const float*)d_in[5];
    const float* conv2_b = (const float*)d_in[6];
    const float* gn0_w   = (const float*)d_in[7];
    const float* gn0_b   = (const float*)d_in[8];
    const float* n1_w    = (const float*)d_in[9];
    const float* n1_b    = (const float*)d_in[10];
    const float* n2_w    = (const float*)d_in[11];
    const float* n2_b    = (const float*)d_in[12];
    const float* bn_g    = (const float*)d_in[13];
    const float* bn_b    = (const float*)d_in[14];
    const float* fc1_w   = (const float*)d_in[15];
    const float* fc1_b   = (const float*)d_in[16];
    const float* shape_w = (const float*)d_in[17];
    const float* shape_b = (const float*)d_in[18];
    const float* vern_w  = (const float*)d_in[19];
    const float* vern_b  = (const float*)d_in[20];
    float* out = (float*)d_out;

    // workspace: doubles first (alignment), then floats
    double* part0 = (double*)d_ws;               // 64*28*16 = 28672 doubles
    float* fbase   = (float*)(part0 + 28672);
    float* h0raw   = fbase;                      // 1605632
    float* h1      = h0raw + 1605632;            // 331776
    float* h2      = h1 + 331776;                // 663552
    float* hv      = h2 + 663552;                // 663552
    float* fc      = hv + 663552;                // 2048

    k_conv0<<<dim3(28, 64), dim3(128), 0, stream>>>(x, conv0_w, conv0_b, h0raw, part0);
    k_conv1_ent<<<dim3(256), dim3(1024), 0, stream>>>(h0raw, part0, gn0_w, gn0_b,
                                                      conv1_w, conv1_b, n1_w, n1_b, h1);
    k_conv2_ent<<<dim3(1024), dim3(512), 0, stream>>>(h1, conv2_w, conv2_b, n2_w, n2_b, h2);
    k_bnstats<<<dim3(162), dim3(256), 0, stream>>>(h2, bn_g, bn_b, hv);
    k_fc1<<<dim3(2048), dim3(256), 0, stream>>>(hv, fc1_w, fc1_b, fc);
    k_heads<<<dim3(1), dim3(64), 0, stream>>>(fc, shape_w, shape_b, vern_w, vern_b, out);
}